// Round 2
// baseline (600.483 us; speedup 1.0000x reference)
//
#include <hip/hip_runtime.h>
#include <math.h>

#define BB 8
#define QQ 100
#define CC 41
#define TT 50
#define HH 256
#define WW 256
#define PP 12544   // = 49 * 256
#define QT 4       // q's per dot-block
#define KS 4       // split-K over P
#define PCH (PP / KS)   // 3136
#define NV  (PCH / 8)   // 392 vec8 chunks

typedef _Float16 f16x2 __attribute__((ext_vector_type(2)));
typedef _Float16 f16x8 __attribute__((ext_vector_type(8)));

#if defined(__has_builtin)
#if __has_builtin(__builtin_amdgcn_fdot2)
#define HAVE_FDOT2 1
#endif
#endif

__device__ __forceinline__ float fdot2_acc(f16x2 a, f16x2 b, float c) {
#ifdef HAVE_FDOT2
    return __builtin_amdgcn_fdot2(a, b, c, false);
#else
    return fmaf((float)a[0], (float)b[0], fmaf((float)a[1], (float)b[1], c));
#endif
}

// Bilinear sample matching F.grid_sample(align_corners=False, padding_mode='zeros')
__device__ __forceinline__ float bilin(const float* __restrict__ m, float cx, float cy) {
    float x = cx * WW - 0.5f;
    float y = cy * HH - 0.5f;
    float x0f = floorf(x), y0f = floorf(y);
    float wx = x - x0f, wy = y - y0f;
    int x0 = (int)x0f, y0 = (int)y0f;
    int x1 = x0 + 1, y1 = y0 + 1;
    float fx0 = (x0 >= 0 && x0 < WW) ? 1.f : 0.f;
    float fx1 = (x1 >= 0 && x1 < WW) ? 1.f : 0.f;
    float fy0 = (y0 >= 0 && y0 < HH) ? 1.f : 0.f;
    float fy1 = (y1 >= 0 && y1 < HH) ? 1.f : 0.f;
    int x0c = min(max(x0, 0), WW - 1);
    int x1c = min(max(x1, 0), WW - 1);
    int y0c = min(max(y0, 0), HH - 1);
    int y1c = min(max(y1, 0), HH - 1);
    float v00 = m[y0c * WW + x0c] * (fx0 * fy0);
    float v01 = m[y0c * WW + x1c] * (fx1 * fy0);
    float v10 = m[y1c * WW + x0c] * (fx0 * fy1);
    float v11 = m[y1c * WW + x1c] * (fx1 * fy1);
    return v00 * (1.f - wx) * (1.f - wy) + v01 * wx * (1.f - wy)
         + v10 * (1.f - wx) * wy + v11 * wx * wy;
}

__device__ __forceinline__ float block_reduce(float v, float* red, int tid) {
    #pragma unroll
    for (int off = 32; off; off >>= 1) v += __shfl_down(v, off, 64);
    if ((tid & 63) == 0) red[tid >> 6] = v;
    __syncthreads();
    return red[0] + red[1] + red[2] + red[3];
}

// blocks [0, BB*TT): sample tgt mask -> tm f16 + tmsum
// blocks [BB*TT, BB*TT+BB*QQ): sample pred mask -> om f16 + nsum/ssum
__global__ __launch_bounds__(256) void sample_kernel(
    const float* __restrict__ tgt_masks, const float* __restrict__ pred_masks,
    const float* __restrict__ coords,
    _Float16* __restrict__ tm, _Float16* __restrict__ om,
    float* __restrict__ tmsum, float* __restrict__ nsum, float* __restrict__ ssum)
{
    __shared__ float red[4];
    __shared__ float red2[4];
    int id = blockIdx.x;
    int tid = threadIdx.x;
    if (id < BB * TT) {
        int b = id / TT;
        const float* m = tgt_masks + (size_t)id * (HH * WW);
        const float2* cd = (const float2*)coords + (size_t)b * PP;
        float ls = 0.f;
        for (int p = tid; p < PP; p += 256) {
            float2 c = cd[p];
            float v = bilin(m, c.x, c.y);
            tm[(size_t)id * PP + p] = (_Float16)v;
            ls += v;
        }
        float tot = block_reduce(ls, red, tid);
        if (tid == 0) tmsum[id] = tot;
    } else {
        int bq = id - BB * TT;
        int b = bq / QQ;
        const float* m = pred_masks + (size_t)bq * (HH * WW);
        const float2* cd = (const float2*)coords + (size_t)b * PP;
        float lneg = 0.f, lsig = 0.f;
        for (int p = tid; p < PP; p += 256) {
            float2 c = cd[p];
            float v = bilin(m, c.x, c.y);
            om[(size_t)bq * PP + p] = (_Float16)v;
            float em = __expf(-fabsf(v));
            lneg += fmaxf(v, 0.f) + __logf(1.f + em);                 // softplus(v)
            lsig += (v >= 0.f) ? 1.f / (1.f + em) : em / (1.f + em);  // sigmoid(v)
        }
        #pragma unroll
        for (int off = 32; off; off >>= 1) {
            lneg += __shfl_down(lneg, off, 64);
            lsig += __shfl_down(lsig, off, 64);
        }
        if ((tid & 63) == 0) { red[tid >> 6] = lneg; red2[tid >> 6] = lsig; }
        __syncthreads();
        if (tid == 0) {
            nsum[bq] = red[0] + red[1] + red[2] + red[3];
            ssum[bq] = red2[0] + red2[1] + red2[2] + red2[3];
        }
    }
}

// grid (B*QQ/QT, KS): per block load om chunk for 4 q's into LDS (+sigmoid),
// each lane owns one (q,t): f16 dot2 accumulation over the P-chunk.
__global__ __launch_bounds__(256) void dot_kernel(
    const _Float16* __restrict__ om, const _Float16* __restrict__ tm,
    float* __restrict__ part_om, float* __restrict__ part_s)
{
    __shared__ f16x8 om_lds[QT][NV];
    __shared__ f16x8 s_lds[QT][NV];
    int bqt = blockIdx.x, ks = blockIdx.y;
    int b = bqt / (QQ / QT), qt = bqt % (QQ / QT);
    int q0 = qt * QT;
    int tid = threadIdx.x;

    // phase A: stage om chunk + sigmoid into LDS
    for (int idx = tid; idx < QT * NV; idx += 256) {
        int q = idx / NV, j = idx % NV;
        const uint4* src = (const uint4*)(om + ((size_t)(b * QQ + q0 + q)) * PP
                                          + (size_t)ks * PCH);
        union { uint4 u; f16x8 v; _Float16 h[8]; } a;
        a.u = src[j];
        f16x8 sv;
        #pragma unroll
        for (int e = 0; e < 8; ++e) {
            float x = (float)a.h[e];
            float em = __expf(-fabsf(x));
            float s = (x >= 0.f) ? 1.f / (1.f + em) : em / (1.f + em);
            sv[e] = (_Float16)s;
        }
        om_lds[q][j] = a.v;
        s_lds[q][j] = sv;
    }
    __syncthreads();

    // phase B: lane t of wave w -> dot(om[q0+w], tm[t]) over this chunk
    int w = tid >> 6, lane = tid & 63;
    if (lane < TT) {
        int q = q0 + w;
        const uint4* trow = (const uint4*)(tm + ((size_t)(b * TT + lane)) * PP
                                           + (size_t)ks * PCH);
        float accO = 0.f, accS = 0.f;
        for (int j = 0; j < NV; ++j) {
            union { uint4 u; f16x2 h[4]; } tv;
            tv.u = trow[j];
            union { f16x8 v; f16x2 h[4]; } o8, s8;
            o8.v = om_lds[w][j];
            s8.v = s_lds[w][j];
            #pragma unroll
            for (int e = 0; e < 4; ++e) {
                accO = fdot2_acc(o8.h[e], tv.h[e], accO);
                accS = fdot2_acc(s8.h[e], tv.h[e], accS);
            }
        }
        size_t o = (((size_t)ks * BB + b) * QQ + q) * TT + lane;
        part_om[o] = accO;
        part_s[o] = accS;
    }
}

__global__ __launch_bounds__(256) void epilogue_kernel(
    const float* __restrict__ part_om, const float* __restrict__ part_s,
    const float* __restrict__ tmsum, const float* __restrict__ nsum,
    const float* __restrict__ ssum, const float* __restrict__ pred_logits,
    const float* __restrict__ pred_obj, const int* __restrict__ labels,
    float* __restrict__ out)
{
    int i = blockIdx.x * 256 + threadIdx.x;
    if (i >= BB * QQ * TT) return;
    int t = i % TT;
    int bq = i / TT;
    int b = bq / QQ;
    float dO = 0.f, dS = 0.f;
    #pragma unroll
    for (int ks = 0; ks < KS; ++ks) {
        dO += part_om[(size_t)ks * (BB * QQ * TT) + i];
        dS += part_s[(size_t)ks * (BB * QQ * TT) + i];
    }
    float ns = nsum[bq], ss = ssum[bq];
    float ts = tmsum[b * TT + t];
    float cmask = (ns - dO) * (1.f / PP);
    float cdice = 1.f - (2.f * dS + 1.f) / (ss + ts + 1.f);
    int label = labels[b * TT + t];
    float a0 = pred_obj[bq * 2], a1 = pred_obj[bq * 2 + 1];
    float prob;
    if (label == CC - 1) {
        prob = 1.f / (1.f + __expf(a0 - a1));
    } else {
        float pc = 1.f / (1.f + __expf(-pred_logits[(size_t)bq * CC + label]));
        float po = 1.f / (1.f + __expf(a1 - a0));
        prob = sqrtf(pc * po);
    }
    out[i] = 5.f * cmask - 2.f * prob + 5.f * cdice;
}

extern "C" void kernel_launch(void* const* d_in, const int* in_sizes, int n_in,
                              void* d_out, int out_size, void* d_ws, size_t ws_size,
                              hipStream_t stream) {
    const float* pred_logits = (const float*)d_in[0];   // [8,100,41]
    const float* pred_obj    = (const float*)d_in[1];   // [8,100,2]
    const float* pred_masks  = (const float*)d_in[2];   // [8,100,256,256]
    const float* tgt_masks   = (const float*)d_in[3];   // [8,50,256,256]
    const int*   tgt_labels  = (const int*)d_in[4];     // [8,50]
    const float* coords      = (const float*)d_in[5];   // [8,12544,2]
    float* out = (float*)d_out;                         // [8,100,50]

    char* ws = (char*)d_ws;
    _Float16* om = (_Float16*)ws;                       // 25,088,000 B
    _Float16* tmm = (_Float16*)(ws + (size_t)BB * QQ * PP * 2);   // 12,544,000 B
    char* p = ws + (size_t)BB * QQ * PP * 2 + (size_t)BB * TT * PP * 2;
    float* part_om = (float*)p;                         // KS*B*Q*T f32 = 640,000 B
    float* part_s  = part_om + (size_t)KS * BB * QQ * TT;
    float* tmsum   = part_s + (size_t)KS * BB * QQ * TT;
    float* nsum    = tmsum + BB * TT;
    float* ssum    = nsum + BB * QQ;

    hipLaunchKernelGGL(sample_kernel, dim3(BB * TT + BB * QQ), dim3(256), 0, stream,
                       tgt_masks, pred_masks, coords, tmm, om, tmsum, nsum, ssum);
    hipLaunchKernelGGL(dot_kernel, dim3(BB * (QQ / QT), KS), dim3(256), 0, stream,
                       om, tmm, part_om, part_s);
    hipLaunchKernelGGL(epilogue_kernel, dim3((BB * QQ * TT + 255) / 256), dim3(256),
                       0, stream,
                       part_om, part_s, tmsum, nsum, ssum,
                       pred_logits, pred_obj, tgt_labels, out);
}

// Round 3
// 288.142 us; speedup vs baseline: 2.0840x; 2.0840x over previous
//
#include <hip/hip_runtime.h>
#include <math.h>

#define BB 8
#define QQ 100
#define CC 41
#define TT 50
#define HH 256
#define WW 256
#define PP 12544   // = 49 * 256
#define QT 4       // q's per dot-block
#define KS 4       // split-K over P
#define PCH (PP / KS)   // 3136
#define NV  (PCH / 8)   // 392 vec8 chunks
#define SROWS1 129      // pass-0 rows [0,129)
#define SROWS2 128      // pass-1 rows [128,256)

typedef _Float16 f16x2 __attribute__((ext_vector_type(2)));
typedef _Float16 f16x8 __attribute__((ext_vector_type(8)));

#if defined(__has_builtin)
#if __has_builtin(__builtin_amdgcn_fdot2)
#define HAVE_FDOT2 1
#endif
#endif

__device__ __forceinline__ float fdot2_acc(f16x2 a, f16x2 b, float c) {
#ifdef HAVE_FDOT2
    return __builtin_amdgcn_fdot2(a, b, c, false);
#else
    return fmaf((float)a[0], (float)b[0], fmaf((float)a[1], (float)b[1], c));
#endif
}

// One block per mask. Two LDS row-passes; coalesced mask load, LDS gathers.
// blocks [0, BB*TT): tgt -> tm f16 + tmsum
// blocks [BB*TT, BB*TT+BB*QQ): pred -> om f16 + nsum/ssum
__global__ __launch_bounds__(1024) void sample_kernel(
    const float* __restrict__ tgt_masks, const float* __restrict__ pred_masks,
    const float* __restrict__ coords,
    _Float16* __restrict__ tm, _Float16* __restrict__ om,
    float* __restrict__ tmsum, float* __restrict__ nsum, float* __restrict__ ssum)
{
    __shared__ float mlds[SROWS1 * WW];   // 132,096 B
    __shared__ float red[16], red2[16];
    int id = blockIdx.x;
    int tid = threadIdx.x;
    bool is_t = id < BB * TT;
    int b;
    const float* m;
    _Float16* dst;
    if (is_t) {
        b = id / TT;
        m = tgt_masks + (size_t)id * (HH * WW);
        dst = tm + (size_t)id * PP;
    } else {
        int bq = id - BB * TT;
        b = bq / QQ;
        m = pred_masks + (size_t)bq * (HH * WW);
        dst = om + (size_t)bq * PP;
    }
    const float2* cd = (const float2*)coords + (size_t)b * PP;

    float ls = 0.f, lneg = 0.f, lsig = 0.f;

    for (int pass = 0; pass < 2; ++pass) {
        int row0 = pass ? 128 : 0;
        int nrow = pass ? SROWS2 : SROWS1;
        const float4* src = (const float4*)(m + (size_t)row0 * WW);
        float4* dl = (float4*)mlds;
        int n4 = nrow * (WW / 4);
        for (int j = tid; j < n4; j += 1024) dl[j] = src[j];
        __syncthreads();

        for (int p = tid; p < PP; p += 1024) {
            float2 c = cd[p];
            float x = c.x * WW - 0.5f;
            float y = c.y * HH - 0.5f;
            float x0f = floorf(x), y0f = floorf(y);
            int y0 = (int)y0f;
            int owner = (y0 >= 128) ? 1 : 0;
            if (owner != pass) continue;
            float wx = x - x0f, wy = y - y0f;
            int x0 = (int)x0f;
            int x1 = x0 + 1, y1 = y0 + 1;
            float fx0 = (x0 >= 0 && x0 < WW) ? 1.f : 0.f;
            float fx1 = (x1 >= 0 && x1 < WW) ? 1.f : 0.f;
            float fy0 = (y0 >= 0 && y0 < HH) ? 1.f : 0.f;
            float fy1 = (y1 >= 0 && y1 < HH) ? 1.f : 0.f;
            int x0c = min(max(x0, 0), WW - 1);
            int x1c = min(max(x1, 0), WW - 1);
            int y0c = min(max(y0, 0), HH - 1) - row0;
            int y1c = min(max(y1, 0), HH - 1) - row0;
            float v00 = mlds[y0c * WW + x0c] * (fx0 * fy0);
            float v01 = mlds[y0c * WW + x1c] * (fx1 * fy0);
            float v10 = mlds[y1c * WW + x0c] * (fx0 * fy1);
            float v11 = mlds[y1c * WW + x1c] * (fx1 * fy1);
            float v = v00 * (1.f - wx) * (1.f - wy) + v01 * wx * (1.f - wy)
                    + v10 * (1.f - wx) * wy + v11 * wx * wy;
            dst[p] = (_Float16)v;
            if (is_t) {
                ls += v;
            } else {
                float em = __expf(-fabsf(v));
                lneg += fmaxf(v, 0.f) + __logf(1.f + em);                 // softplus
                lsig += (v >= 0.f) ? 1.f / (1.f + em) : em / (1.f + em);  // sigmoid
            }
        }
        __syncthreads();
    }

    // block reduction over 16 waves
    #pragma unroll
    for (int off = 32; off; off >>= 1) {
        ls   += __shfl_down(ls, off, 64);
        lneg += __shfl_down(lneg, off, 64);
        lsig += __shfl_down(lsig, off, 64);
    }
    if ((tid & 63) == 0) { red[tid >> 6] = is_t ? ls : lneg; red2[tid >> 6] = lsig; }
    __syncthreads();
    if (tid == 0) {
        float s1 = 0.f, s2 = 0.f;
        #pragma unroll
        for (int w = 0; w < 16; ++w) { s1 += red[w]; s2 += red2[w]; }
        if (is_t) tmsum[id] = s1;
        else { nsum[id - BB * TT] = s1; ssum[id - BB * TT] = s2; }
    }
}

// grid (B*QQ/QT, KS): per block load om chunk for 4 q's into LDS (+sigmoid),
// each lane owns one (q,t): f16 dot2 accumulation over the P-chunk.
__global__ __launch_bounds__(256) void dot_kernel(
    const _Float16* __restrict__ om, const _Float16* __restrict__ tm,
    float* __restrict__ part_om, float* __restrict__ part_s)
{
    __shared__ f16x8 om_lds[QT][NV];
    __shared__ f16x8 s_lds[QT][NV];
    int bqt = blockIdx.x, ks = blockIdx.y;
    int b = bqt / (QQ / QT), qt = bqt % (QQ / QT);
    int q0 = qt * QT;
    int tid = threadIdx.x;

    for (int idx = tid; idx < QT * NV; idx += 256) {
        int q = idx / NV, j = idx % NV;
        const uint4* src = (const uint4*)(om + ((size_t)(b * QQ + q0 + q)) * PP
                                          + (size_t)ks * PCH);
        union { uint4 u; f16x8 v; _Float16 h[8]; } a;
        a.u = src[j];
        f16x8 sv;
        #pragma unroll
        for (int e = 0; e < 8; ++e) {
            float x = (float)a.h[e];
            float em = __expf(-fabsf(x));
            float s = (x >= 0.f) ? 1.f / (1.f + em) : em / (1.f + em);
            sv[e] = (_Float16)s;
        }
        om_lds[q][j] = a.v;
        s_lds[q][j] = sv;
    }
    __syncthreads();

    int w = tid >> 6, lane = tid & 63;
    if (lane < TT) {
        int q = q0 + w;
        const uint4* trow = (const uint4*)(tm + ((size_t)(b * TT + lane)) * PP
                                           + (size_t)ks * PCH);
        float accO = 0.f, accS = 0.f;
        for (int j = 0; j < NV; ++j) {
            union { uint4 u; f16x2 h[4]; } tv;
            tv.u = trow[j];
            union { f16x8 v; f16x2 h[4]; } o8, s8;
            o8.v = om_lds[w][j];
            s8.v = s_lds[w][j];
            #pragma unroll
            for (int e = 0; e < 4; ++e) {
                accO = fdot2_acc(o8.h[e], tv.h[e], accO);
                accS = fdot2_acc(s8.h[e], tv.h[e], accS);
            }
        }
        size_t o = (((size_t)ks * BB + b) * QQ + q) * TT + lane;
        part_om[o] = accO;
        part_s[o] = accS;
    }
}

__global__ __launch_bounds__(256) void epilogue_kernel(
    const float* __restrict__ part_om, const float* __restrict__ part_s,
    const float* __restrict__ tmsum, const float* __restrict__ nsum,
    const float* __restrict__ ssum, const float* __restrict__ pred_logits,
    const float* __restrict__ pred_obj, const int* __restrict__ labels,
    float* __restrict__ out)
{
    int i = blockIdx.x * 256 + threadIdx.x;
    if (i >= BB * QQ * TT) return;
    int t = i % TT;
    int bq = i / TT;
    int b = bq / QQ;
    float dO = 0.f, dS = 0.f;
    #pragma unroll
    for (int ks = 0; ks < KS; ++ks) {
        dO += part_om[(size_t)ks * (BB * QQ * TT) + i];
        dS += part_s[(size_t)ks * (BB * QQ * TT) + i];
    }
    float ns = nsum[bq], ss = ssum[bq];
    float ts = tmsum[b * TT + t];
    float cmask = (ns - dO) * (1.f / PP);
    float cdice = 1.f - (2.f * dS + 1.f) / (ss + ts + 1.f);
    int label = labels[b * TT + t];
    float a0 = pred_obj[bq * 2], a1 = pred_obj[bq * 2 + 1];
    float prob;
    if (label == CC - 1) {
        prob = 1.f / (1.f + __expf(a0 - a1));
    } else {
        float pc = 1.f / (1.f + __expf(-pred_logits[(size_t)bq * CC + label]));
        float po = 1.f / (1.f + __expf(a1 - a0));
        prob = sqrtf(pc * po);
    }
    out[i] = 5.f * cmask - 2.f * prob + 5.f * cdice;
}

extern "C" void kernel_launch(void* const* d_in, const int* in_sizes, int n_in,
                              void* d_out, int out_size, void* d_ws, size_t ws_size,
                              hipStream_t stream) {
    const float* pred_logits = (const float*)d_in[0];   // [8,100,41]
    const float* pred_obj    = (const float*)d_in[1];   // [8,100,2]
    const float* pred_masks  = (const float*)d_in[2];   // [8,100,256,256]
    const float* tgt_masks   = (const float*)d_in[3];   // [8,50,256,256]
    const int*   tgt_labels  = (const int*)d_in[4];     // [8,50]
    const float* coords      = (const float*)d_in[5];   // [8,12544,2]
    float* out = (float*)d_out;                         // [8,100,50]

    char* ws = (char*)d_ws;
    _Float16* om = (_Float16*)ws;                       // 25,088,000 B
    _Float16* tmm = (_Float16*)(ws + (size_t)BB * QQ * PP * 2);   // 12,544,000 B
    char* p = ws + (size_t)BB * QQ * PP * 2 + (size_t)BB * TT * PP * 2;
    float* part_om = (float*)p;                         // KS*B*Q*T f32
    float* part_s  = part_om + (size_t)KS * BB * QQ * TT;
    float* tmsum   = part_s + (size_t)KS * BB * QQ * TT;
    float* nsum    = tmsum + BB * TT;
    float* ssum    = nsum + BB * QQ;

    hipLaunchKernelGGL(sample_kernel, dim3(BB * TT + BB * QQ), dim3(1024), 0, stream,
                       tgt_masks, pred_masks, coords, tmm, om, tmsum, nsum, ssum);
    hipLaunchKernelGGL(dot_kernel, dim3(BB * (QQ / QT), KS), dim3(256), 0, stream,
                       om, tmm, part_om, part_s);
    hipLaunchKernelGGL(epilogue_kernel, dim3((BB * QQ * TT + 255) / 256), dim3(256),
                       0, stream,
                       part_om, part_s, tmsum, nsum, ssum,
                       pred_logits, pred_obj, tgt_labels, out);
}

// Round 5
// 186.341 us; speedup vs baseline: 3.2225x; 1.5463x over previous
//
#include <hip/hip_runtime.h>
#include <math.h>

#define BB 8
#define QQ 100
#define CC 41
#define TT 50
#define HH 256
#define WW 256
#define PP 12544        // = 49 * 256
#define QT 4            // q's per dot-block (one per wave)
#define KS 4            // split-K over P
#define PCH (PP / KS)   // 3136
#define PSUB 224        // p sub-chunk staged in LDS
#define NSUB (PCH / PSUB)   // 14
#define TSTR 228        // tm_lds row stride (f16)

typedef _Float16 f16x2 __attribute__((ext_vector_type(2)));
typedef _Float16 f16x4 __attribute__((ext_vector_type(4)));

#if defined(__has_builtin)
#if __has_builtin(__builtin_amdgcn_fdot2)
#define HAVE_FDOT2 1
#endif
#if __has_builtin(__builtin_amdgcn_cvt_pk_fp8_f32) && __has_builtin(__builtin_amdgcn_cvt_f32_fp8)
#define HAVE_FP8CVT 1
#endif
#endif

__device__ __forceinline__ float fdot2_acc(f16x2 a, f16x2 b, float c) {
#ifdef HAVE_FDOT2
    return __builtin_amdgcn_fdot2(a, b, c, false);
#else
    return fmaf((float)a[0], (float)b[0], fmaf((float)a[1], (float)b[1], c));
#endif
}

__device__ __forceinline__ unsigned int cvt1_e4m3_sw(float x) {
    unsigned int u = __float_as_uint(x);
    unsigned int s = (u >> 24) & 0x80u;
    float ax = fminf(fabsf(x), 448.f);
    if (ax < 0.015625f) {                       // subnormal: m * 2^-9
        unsigned int m = (unsigned int)rintf(ax * 512.f);
        return s | m;
    }
    unsigned int v = __float_as_uint(ax);
    v += 0x7FFFFu + ((v >> 20) & 1u);           // RNE to 3 mantissa bits
    int e = (int)(v >> 23) - 127;
    unsigned int m = (v >> 20) & 7u;
    if (e < -6) { m = (unsigned int)rintf(ax * 512.f); return s | m; }
    unsigned int ee = (unsigned int)(e + 7);
    if (ee >= 16u) { ee = 15u; m = 6u; }
    return s | (ee << 3) | m;
}

template <bool HI>
__device__ __forceinline__ unsigned int pack2_e4m3(float a, float b, unsigned int old) {
#ifdef HAVE_FP8CVT
    return (unsigned int)__builtin_amdgcn_cvt_pk_fp8_f32(a, b, (int)old, HI);
#else
    unsigned int p = (cvt1_e4m3_sw(a) | (cvt1_e4m3_sw(b) << 8)) << (HI ? 16 : 0);
    unsigned int mask = HI ? 0x0000FFFFu : 0xFFFF0000u;
    return (old & mask) | p;
#endif
}

__device__ __forceinline__ float e4m3_to_f32(unsigned int byte) {
#ifdef HAVE_FP8CVT
    return __builtin_amdgcn_cvt_f32_fp8((int)byte, 0);
#else
    unsigned int s = byte >> 7, e = (byte >> 3) & 15u, m = byte & 7u;
    float v = e ? __uint_as_float(((e + 120u) << 23) | (m << 20))
                : (float)m * 0.001953125f;
    return s ? -v : v;
#endif
}

// One block per mask; FULL mask in LDS as fp8 (64 KB) -> 2 blocks/CU.
// blocks [0, BB*TT): tgt -> tm f16 + tmsum
// blocks [BB*TT, ...): pred -> om f16 + nsum/ssum
__global__ __launch_bounds__(1024, 8) void sample_kernel(
    const float* __restrict__ tgt_masks, const float* __restrict__ pred_masks,
    const float* __restrict__ coords,
    _Float16* __restrict__ tm, _Float16* __restrict__ om,
    float* __restrict__ tmsum, float* __restrict__ nsum, float* __restrict__ ssum)
{
    __shared__ unsigned char mlds[HH * WW];   // fp8 e4m3, 65536 B
    __shared__ float red[16], red2[16];
    int id = blockIdx.x;
    int tid = threadIdx.x;
    bool is_t = id < BB * TT;
    int b;
    const float* m;
    _Float16* dst;
    if (is_t) {
        b = id / TT;
        m = tgt_masks + (size_t)id * (HH * WW);
        dst = tm + (size_t)id * PP;
    } else {
        int bq = id - BB * TT;
        b = bq / QQ;
        m = pred_masks + (size_t)bq * (HH * WW);
        dst = om + (size_t)bq * PP;
    }
    const float2* cd = (const float2*)coords + (size_t)b * PP;

    // ---- load mask, convert to fp8, store to LDS (coalesced) ----
    {
        const float4* src4 = (const float4*)m;
        unsigned int* dl = (unsigned int*)mlds;
        #pragma unroll 4
        for (int j = 0; j < 16; ++j) {
            int idx = j * 1024 + tid;
            float4 v = src4[idx];
            unsigned int pk = pack2_e4m3<false>(v.x, v.y, 0u);
            pk = pack2_e4m3<true>(v.z, v.w, pk);
            dl[idx] = pk;
        }
    }
    __syncthreads();

    // ---- sample all points from LDS ----
    float ls = 0.f, lneg = 0.f, lsig = 0.f;
    for (int p = tid; p < PP; p += 1024) {
        float2 c = cd[p];
        float x = c.x * WW - 0.5f;
        float y = c.y * HH - 0.5f;
        float x0f = floorf(x), y0f = floorf(y);
        float wx = x - x0f, wy = y - y0f;
        int x0 = (int)x0f, y0 = (int)y0f;
        int x1 = x0 + 1, y1 = y0 + 1;
        float fx0 = (x0 >= 0 && x0 < WW) ? 1.f : 0.f;
        float fx1 = (x1 >= 0 && x1 < WW) ? 1.f : 0.f;
        float fy0 = (y0 >= 0 && y0 < HH) ? 1.f : 0.f;
        float fy1 = (y1 >= 0 && y1 < HH) ? 1.f : 0.f;
        int x0c = min(max(x0, 0), WW - 1);
        int x1c = min(max(x1, 0), WW - 1);
        int y0c = min(max(y0, 0), HH - 1);
        int y1c = min(max(y1, 0), HH - 1);
        float v00 = e4m3_to_f32(mlds[y0c * WW + x0c]) * (fx0 * fy0);
        float v01 = e4m3_to_f32(mlds[y0c * WW + x1c]) * (fx1 * fy0);
        float v10 = e4m3_to_f32(mlds[y1c * WW + x0c]) * (fx0 * fy1);
        float v11 = e4m3_to_f32(mlds[y1c * WW + x1c]) * (fx1 * fy1);
        float v = v00 * (1.f - wx) * (1.f - wy) + v01 * wx * (1.f - wy)
                + v10 * (1.f - wx) * wy + v11 * wx * wy;
        dst[p] = (_Float16)v;
        if (is_t) {
            ls += v;
        } else {
            float em = __expf(-fabsf(v));
            lneg += fmaxf(v, 0.f) + __logf(1.f + em);                 // softplus
            lsig += (v >= 0.f) ? 1.f / (1.f + em) : em / (1.f + em);  // sigmoid
        }
    }

    // ---- block reduction (16 waves) ----
    #pragma unroll
    for (int off = 32; off; off >>= 1) {
        ls   += __shfl_down(ls, off, 64);
        lneg += __shfl_down(lneg, off, 64);
        lsig += __shfl_down(lsig, off, 64);
    }
    if ((tid & 63) == 0) { red[tid >> 6] = is_t ? ls : lneg; red2[tid >> 6] = lsig; }
    __syncthreads();
    if (tid == 0) {
        float s1 = 0.f, s2 = 0.f;
        #pragma unroll
        for (int w = 0; w < 16; ++w) { s1 += red[w]; s2 += red2[w]; }
        if (is_t) tmsum[id] = s1;
        else { nsum[id - BB * TT] = s1; ssum[id - BB * TT] = s2; }
    }
}

// grid (BB*25, KS): wave w handles q = qt*4+w, lane = t. om+sig staged in LDS
// for the whole chunk; tm staged per 224-p sub-chunk COALESCED, then read per
// lane (row stride 228 f16 -> spread banks).
__global__ __launch_bounds__(256) void dot_kernel(
    const _Float16* __restrict__ om, const _Float16* __restrict__ tm,
    float* __restrict__ part_om, float* __restrict__ part_s)
{
    __shared__ _Float16 om_lds[QT][PCH];      // 25088 B
    __shared__ _Float16 sig_lds[QT][PCH];     // 25088 B
    __shared__ _Float16 tm_lds[TT][TSTR];     // 22800 B
    int b = blockIdx.x / 25, qt = blockIdx.x % 25, ks = blockIdx.y;
    int q0 = qt * QT;
    int tid = threadIdx.x;
    int w = tid >> 6, lane = tid & 63;

    // ---- stage om + sigmoid(om) for 4 q's, this K-chunk ----
    for (int idx = tid; idx < QT * (PCH / 8); idx += 256) {
        int q = idx / (PCH / 8), j = idx % (PCH / 8);
        union { uint4 u; _Float16 h[8]; } a, sg;
        a.u = *(const uint4*)(om + ((size_t)(b * QQ + q0 + q)) * PP
                              + (size_t)ks * PCH + j * 8);
        #pragma unroll
        for (int e = 0; e < 8; ++e) {
            float xv = (float)a.h[e];
            float em = __expf(-fabsf(xv));
            sg.h[e] = (_Float16)((xv >= 0.f) ? 1.f / (1.f + em) : em / (1.f + em));
        }
        *(uint4*)&om_lds[q][j * 8] = a.u;
        *(uint4*)&sig_lds[q][j * 8] = sg.u;
    }

    float accOa = 0.f, accOb = 0.f, accSa = 0.f, accSb = 0.f;

    for (int sc = 0; sc < NSUB; ++sc) {
        __syncthreads();   // previous sub-chunk consumed (also orders om staging)
        for (int idx = tid; idx < TT * (PSUB / 8); idx += 256) {
            int t = idx / (PSUB / 8), j8 = idx % (PSUB / 8);
            union { uint4 u4; uint2 u2[2]; } r;
            r.u4 = *(const uint4*)(tm + ((size_t)(b * TT + t)) * PP
                                   + (size_t)ks * PCH + sc * PSUB + j8 * 8);
            *(uint2*)&tm_lds[t][j8 * 8] = r.u2[0];
            *(uint2*)&tm_lds[t][j8 * 8 + 4] = r.u2[1];
        }
        __syncthreads();
        if (lane < TT) {
            const _Float16* trow = &tm_lds[lane][0];
            const _Float16* orow = &om_lds[w][sc * PSUB];
            const _Float16* srow = &sig_lds[w][sc * PSUB];
            #pragma unroll 8
            for (int j = 0; j < PSUB / 4; ++j) {
                union { f16x4 v; f16x2 h[2]; } tv, ov, sv;
                tv.v = *(const f16x4*)(trow + 4 * j);
                ov.v = *(const f16x4*)(orow + 4 * j);
                sv.v = *(const f16x4*)(srow + 4 * j);
                accOa = fdot2_acc(ov.h[0], tv.h[0], accOa);
                accOb = fdot2_acc(ov.h[1], tv.h[1], accOb);
                accSa = fdot2_acc(sv.h[0], tv.h[0], accSa);
                accSb = fdot2_acc(sv.h[1], tv.h[1], accSb);
            }
        }
    }
    if (lane < TT) {
        size_t o = (((size_t)ks * BB + b) * QQ + (q0 + w)) * TT + lane;
        part_om[o] = accOa + accOb;
        part_s[o]  = accSa + accSb;
    }
}

__global__ __launch_bounds__(256) void epilogue_kernel(
    const float* __restrict__ part_om, const float* __restrict__ part_s,
    const float* __restrict__ tmsum, const float* __restrict__ nsum,
    const float* __restrict__ ssum, const float* __restrict__ pred_logits,
    const float* __restrict__ pred_obj, const int* __restrict__ labels,
    float* __restrict__ out)
{
    int i = blockIdx.x * 256 + threadIdx.x;
    if (i >= BB * QQ * TT) return;
    int t = i % TT;
    int bq = i / TT;
    int b = bq / QQ;
    float dO = 0.f, dS = 0.f;
    #pragma unroll
    for (int ks = 0; ks < KS; ++ks) {
        dO += part_om[(size_t)ks * (BB * QQ * TT) + i];
        dS += part_s[(size_t)ks * (BB * QQ * TT) + i];
    }
    float ns = nsum[bq], ss = ssum[bq];
    float ts = tmsum[b * TT + t];
    float cmask = (ns - dO) * (1.f / PP);
    float cdice = 1.f - (2.f * dS + 1.f) / (ss + ts + 1.f);
    int label = labels[b * TT + t];
    float a0 = pred_obj[bq * 2], a1 = pred_obj[bq * 2 + 1];
    float prob;
    if (label == CC - 1) {
        prob = 1.f / (1.f + __expf(a0 - a1));
    } else {
        float pc = 1.f / (1.f + __expf(-pred_logits[(size_t)bq * CC + label]));
        float po = 1.f / (1.f + __expf(a1 - a0));
        prob = sqrtf(pc * po);
    }
    out[i] = 5.f * cmask - 2.f * prob + 5.f * cdice;
}

extern "C" void kernel_launch(void* const* d_in, const int* in_sizes, int n_in,
                              void* d_out, int out_size, void* d_ws, size_t ws_size,
                              hipStream_t stream) {
    const float* pred_logits = (const float*)d_in[0];   // [8,100,41]
    const float* pred_obj    = (const float*)d_in[1];   // [8,100,2]
    const float* pred_masks  = (const float*)d_in[2];   // [8,100,256,256]
    const float* tgt_masks   = (const float*)d_in[3];   // [8,50,256,256]
    const int*   tgt_labels  = (const int*)d_in[4];     // [8,50]
    const float* coords      = (const float*)d_in[5];   // [8,12544,2]
    float* out = (float*)d_out;                         // [8,100,50]

    char* ws = (char*)d_ws;
    _Float16* om = (_Float16*)ws;                       // 25,088,000 B
    _Float16* tmm = (_Float16*)(ws + (size_t)BB * QQ * PP * 2);   // 12,544,000 B
    char* p = ws + (size_t)BB * QQ * PP * 2 + (size_t)BB * TT * PP * 2;
    float* part_om = (float*)p;                         // KS*B*Q*T f32
    float* part_s  = part_om + (size_t)KS * BB * QQ * TT;
    float* tmsum   = part_s + (size_t)KS * BB * QQ * TT;
    float* nsum    = tmsum + BB * TT;
    float* ssum    = nsum + BB * QQ;

    hipLaunchKernelGGL(sample_kernel, dim3(BB * TT + BB * QQ), dim3(1024), 0, stream,
                       tgt_masks, pred_masks, coords, tmm, om, tmsum, nsum, ssum);
    hipLaunchKernelGGL(dot_kernel, dim3(BB * 25, KS), dim3(256), 0, stream,
                       om, tmm, part_om, part_s);
    hipLaunchKernelGGL(epilogue_kernel, dim3((BB * QQ * TT + 255) / 256), dim3(256),
                       0, stream,
                       part_om, part_s, tmsum, nsum, ssum,
                       pred_logits, pred_obj, tgt_labels, out);
}

// Round 6
// 120.267 us; speedup vs baseline: 4.9929x; 1.5494x over previous
//
#include <hip/hip_runtime.h>
#include <math.h>

#define BB 8
#define QQ 100
#define CC 41
#define TT 50
#define HH 256
#define WW 256
#define PP 12544        // = 49 * 256
#define QP 112          // padded Q rows (7 * 16)
#define TP 64           // padded T rows (4 * 16)
#define KS 8            // split-K over P
#define KCH (PP / KS)   // 1568 = 49 * 32

typedef _Float16 f16x8 __attribute__((ext_vector_type(8)));
typedef float f32x4 __attribute__((ext_vector_type(4)));

#if defined(__has_builtin)
#if __has_builtin(__builtin_amdgcn_cvt_pk_fp8_f32) && __has_builtin(__builtin_amdgcn_cvt_f32_fp8)
#define HAVE_FP8CVT 1
#endif
#endif

__device__ __forceinline__ unsigned int cvt1_e4m3_sw(float x) {
    unsigned int u = __float_as_uint(x);
    unsigned int s = (u >> 24) & 0x80u;
    float ax = fminf(fabsf(x), 448.f);
    if (ax < 0.015625f) {
        unsigned int m = (unsigned int)rintf(ax * 512.f);
        return s | m;
    }
    unsigned int v = __float_as_uint(ax);
    v += 0x7FFFFu + ((v >> 20) & 1u);
    int e = (int)(v >> 23) - 127;
    unsigned int m = (v >> 20) & 7u;
    if (e < -6) { m = (unsigned int)rintf(ax * 512.f); return s | m; }
    unsigned int ee = (unsigned int)(e + 7);
    if (ee >= 16u) { ee = 15u; m = 6u; }
    return s | (ee << 3) | m;
}

template <bool HI>
__device__ __forceinline__ unsigned int pack2_e4m3(float a, float b, unsigned int old) {
#ifdef HAVE_FP8CVT
    return (unsigned int)__builtin_amdgcn_cvt_pk_fp8_f32(a, b, (int)old, HI);
#else
    unsigned int p = (cvt1_e4m3_sw(a) | (cvt1_e4m3_sw(b) << 8)) << (HI ? 16 : 0);
    unsigned int mask = HI ? 0x0000FFFFu : 0xFFFF0000u;
    return (old & mask) | p;
#endif
}

__device__ __forceinline__ float e4m3_to_f32(unsigned int byte) {
#ifdef HAVE_FP8CVT
    return __builtin_amdgcn_cvt_f32_fp8((int)byte, 0);
#else
    unsigned int s = byte >> 7, e = (byte >> 3) & 15u, m = byte & 7u;
    float v = e ? __uint_as_float(((e + 120u) << 23) | (m << 20))
                : (float)m * 0.001953125f;
    return s ? -v : v;
#endif
}

__device__ __forceinline__ float samp(const unsigned char* __restrict__ mlds, float2 c) {
    float x = fmaf(c.x, 256.f, -0.5f);
    float y = fmaf(c.y, 256.f, -0.5f);
    float x0f = floorf(x), y0f = floorf(y);
    float wx = x - x0f, wy = y - y0f;
    int x0 = (int)x0f, y0 = (int)y0f;
    float fx0 = (x0 >= 0) ? 1.f : 0.f, fx1 = (x0 < 255) ? 1.f : 0.f;
    float fy0 = (y0 >= 0) ? 1.f : 0.f, fy1 = (y0 < 255) ? 1.f : 0.f;
    int x0c = max(x0, 0), x1c = min(x0 + 1, 255);
    int r0 = max(y0, 0) << 8, r1 = (min(y0 + 1, 255)) << 8;
    float v00 = e4m3_to_f32(mlds[r0 + x0c]);
    float v01 = e4m3_to_f32(mlds[r0 + x1c]);
    float v10 = e4m3_to_f32(mlds[r1 + x0c]);
    float v11 = e4m3_to_f32(mlds[r1 + x1c]);
    float wxa = (1.f - wx) * fx0, wxb = wx * fx1;
    float wya = (1.f - wy) * fy0, wyb = wy * fy1;
    return wya * fmaf(wxa, v00, wxb * v01) + wyb * fmaf(wxa, v10, wxb * v11);
}

// One block per mask; full mask fp8 in LDS (64 KB) -> 2 blocks/CU.
__global__ __launch_bounds__(1024, 8) void sample_kernel(
    const float* __restrict__ tgt_masks, const float* __restrict__ pred_masks,
    const float* __restrict__ coords,
    _Float16* __restrict__ tm, _Float16* __restrict__ om, _Float16* __restrict__ sg,
    float* __restrict__ tmsum, float* __restrict__ nsum, float* __restrict__ ssum)
{
    __shared__ unsigned char mlds[HH * WW];
    __shared__ float red[16], red2[16];
    int id = blockIdx.x;
    int tid = threadIdx.x;
    bool is_t = id < BB * TT;
    int b;
    const float* m;
    _Float16* dst;
    _Float16* dsg = nullptr;
    if (is_t) {
        b = id / TT;
        m = tgt_masks + (size_t)id * (HH * WW);
        dst = tm + ((size_t)b * TP + (id % TT)) * PP;
    } else {
        int bq = id - BB * TT;
        b = bq / QQ;
        int q = bq % QQ;
        m = pred_masks + (size_t)bq * (HH * WW);
        dst = om + ((size_t)b * QP + q) * PP;
        dsg = sg + ((size_t)b * QP + q) * PP;
    }
    const float2* cd = (const float2*)coords + (size_t)b * PP;

    // ---- load mask -> fp8 LDS, two 8-deep batches for MLP ----
    {
        const float4* s4 = (const float4*)m;
        unsigned int* dl = (unsigned int*)mlds;
        float4 v0 = s4[tid], v1 = s4[tid + 1024], v2 = s4[tid + 2048], v3 = s4[tid + 3072];
        float4 v4 = s4[tid + 4096], v5 = s4[tid + 5120], v6 = s4[tid + 6144], v7 = s4[tid + 7168];
        unsigned int pk;
        pk = pack2_e4m3<false>(v0.x, v0.y, 0u); dl[tid]        = pack2_e4m3<true>(v0.z, v0.w, pk);
        pk = pack2_e4m3<false>(v1.x, v1.y, 0u); dl[tid + 1024] = pack2_e4m3<true>(v1.z, v1.w, pk);
        pk = pack2_e4m3<false>(v2.x, v2.y, 0u); dl[tid + 2048] = pack2_e4m3<true>(v2.z, v2.w, pk);
        pk = pack2_e4m3<false>(v3.x, v3.y, 0u); dl[tid + 3072] = pack2_e4m3<true>(v3.z, v3.w, pk);
        pk = pack2_e4m3<false>(v4.x, v4.y, 0u); dl[tid + 4096] = pack2_e4m3<true>(v4.z, v4.w, pk);
        pk = pack2_e4m3<false>(v5.x, v5.y, 0u); dl[tid + 5120] = pack2_e4m3<true>(v5.z, v5.w, pk);
        pk = pack2_e4m3<false>(v6.x, v6.y, 0u); dl[tid + 6144] = pack2_e4m3<true>(v6.z, v6.w, pk);
        pk = pack2_e4m3<false>(v7.x, v7.y, 0u); dl[tid + 7168] = pack2_e4m3<true>(v7.z, v7.w, pk);
        float4 u0 = s4[tid + 8192], u1 = s4[tid + 9216], u2 = s4[tid + 10240], u3 = s4[tid + 11264];
        float4 u4 = s4[tid + 12288], u5 = s4[tid + 13312], u6 = s4[tid + 14336], u7 = s4[tid + 15360];
        pk = pack2_e4m3<false>(u0.x, u0.y, 0u); dl[tid + 8192]  = pack2_e4m3<true>(u0.z, u0.w, pk);
        pk = pack2_e4m3<false>(u1.x, u1.y, 0u); dl[tid + 9216]  = pack2_e4m3<true>(u1.z, u1.w, pk);
        pk = pack2_e4m3<false>(u2.x, u2.y, 0u); dl[tid + 10240] = pack2_e4m3<true>(u2.z, u2.w, pk);
        pk = pack2_e4m3<false>(u3.x, u3.y, 0u); dl[tid + 11264] = pack2_e4m3<true>(u3.z, u3.w, pk);
        pk = pack2_e4m3<false>(u4.x, u4.y, 0u); dl[tid + 12288] = pack2_e4m3<true>(u4.z, u4.w, pk);
        pk = pack2_e4m3<false>(u5.x, u5.y, 0u); dl[tid + 13312] = pack2_e4m3<true>(u5.z, u5.w, pk);
        pk = pack2_e4m3<false>(u6.x, u6.y, 0u); dl[tid + 14336] = pack2_e4m3<true>(u6.z, u6.w, pk);
        pk = pack2_e4m3<false>(u7.x, u7.y, 0u); dl[tid + 15360] = pack2_e4m3<true>(u7.z, u7.w, pk);
    }
    __syncthreads();

    float sA = 0.f, sB = 0.f;   // tm sums (2 chains)
    float nA = 0.f, nB = 0.f;   // softplus sums
    float gA = 0.f, gB = 0.f;   // sigmoid sums

    if (is_t) {
        #pragma unroll
        for (int g = 0; g < 3; ++g) {
            int p0 = g * 4096 + tid;
            float2 c0 = cd[p0], c1 = cd[p0 + 1024], c2 = cd[p0 + 2048], c3 = cd[p0 + 3072];
            float v0 = samp(mlds, c0), v1 = samp(mlds, c1);
            float v2 = samp(mlds, c2), v3 = samp(mlds, c3);
            dst[p0] = (_Float16)v0;
            dst[p0 + 1024] = (_Float16)v1;
            dst[p0 + 2048] = (_Float16)v2;
            dst[p0 + 3072] = (_Float16)v3;
            sA += v0 + v2; sB += v1 + v3;
        }
        if (tid < 256) {
            int p = 12288 + tid;
            float v = samp(mlds, cd[p]);
            dst[p] = (_Float16)v;
            sA += v;
        }
    } else {
        #pragma unroll
        for (int g = 0; g < 3; ++g) {
            int p0 = g * 4096 + tid;
            float2 c0 = cd[p0], c1 = cd[p0 + 1024], c2 = cd[p0 + 2048], c3 = cd[p0 + 3072];
            float v0 = samp(mlds, c0), v1 = samp(mlds, c1);
            float v2 = samp(mlds, c2), v3 = samp(mlds, c3);
            dst[p0] = (_Float16)v0;
            dst[p0 + 1024] = (_Float16)v1;
            dst[p0 + 2048] = (_Float16)v2;
            dst[p0 + 3072] = (_Float16)v3;
            float e0 = __expf(-fabsf(v0)), e1 = __expf(-fabsf(v1));
            float e2 = __expf(-fabsf(v2)), e3 = __expf(-fabsf(v3));
            float r0 = 1.f / (1.f + e0), r1 = 1.f / (1.f + e1);
            float r2 = 1.f / (1.f + e2), r3 = 1.f / (1.f + e3);
            float g0 = (v0 >= 0.f) ? r0 : e0 * r0, g1 = (v1 >= 0.f) ? r1 : e1 * r1;
            float g2 = (v2 >= 0.f) ? r2 : e2 * r2, g3 = (v3 >= 0.f) ? r3 : e3 * r3;
            dsg[p0] = (_Float16)g0;
            dsg[p0 + 1024] = (_Float16)g1;
            dsg[p0 + 2048] = (_Float16)g2;
            dsg[p0 + 3072] = (_Float16)g3;
            nA += fmaxf(v0, 0.f) + __logf(1.f + e0) + fmaxf(v2, 0.f) + __logf(1.f + e2);
            nB += fmaxf(v1, 0.f) + __logf(1.f + e1) + fmaxf(v3, 0.f) + __logf(1.f + e3);
            gA += g0 + g2; gB += g1 + g3;
        }
        if (tid < 256) {
            int p = 12288 + tid;
            float v = samp(mlds, cd[p]);
            dst[p] = (_Float16)v;
            float e = __expf(-fabsf(v));
            float r = 1.f / (1.f + e);
            float gg = (v >= 0.f) ? r : e * r;
            dsg[p] = (_Float16)gg;
            nA += fmaxf(v, 0.f) + __logf(1.f + e);
            gA += gg;
        }
    }

    float l1 = is_t ? (sA + sB) : (nA + nB);
    float l2 = gA + gB;
    #pragma unroll
    for (int off = 32; off; off >>= 1) {
        l1 += __shfl_down(l1, off, 64);
        l2 += __shfl_down(l2, off, 64);
    }
    if ((tid & 63) == 0) { red[tid >> 6] = l1; red2[tid >> 6] = l2; }
    __syncthreads();
    if (tid == 0) {
        float t1 = 0.f, t2 = 0.f;
        #pragma unroll
        for (int w = 0; w < 16; ++w) { t1 += red[w]; t2 += red2[w]; }
        if (is_t) tmsum[id] = t1;
        else { nsum[id - BB * TT] = t1; ssum[id - BB * TT] = t2; }
    }
}

// grid (7 qt, 8 b, KS). 4 waves; wave w owns t-tile w. C1=om.tm^T, C2=sig.tm^T.
__global__ __launch_bounds__(256) void dot_mfma_kernel(
    const _Float16* __restrict__ om, const _Float16* __restrict__ sg,
    const _Float16* __restrict__ tm,
    float* __restrict__ part_om, float* __restrict__ part_s)
{
    int qt = blockIdx.x, b = blockIdx.y, ks = blockIdx.z;
    int tid = threadIdx.x, lane = tid & 63, w = tid >> 6;
    int ra = lane & 15;           // row within 16-tile
    int ko = (lane >> 4) * 8;     // k sub-offset
    const _Float16* pa = om + ((size_t)(b * QP + qt * 16 + ra)) * PP + ks * KCH + ko;
    const _Float16* ps = sg + ((size_t)(b * QP + qt * 16 + ra)) * PP + ks * KCH + ko;
    const _Float16* pb = tm + ((size_t)(b * TP + w * 16 + ra)) * PP + ks * KCH + ko;
    f32x4 accO = {0.f, 0.f, 0.f, 0.f};
    f32x4 accS = {0.f, 0.f, 0.f, 0.f};
    #pragma unroll 7
    for (int k = 0; k < KCH / 32; ++k) {
        f16x8 a = *(const f16x8*)(pa + (size_t)k * 32);
        f16x8 s = *(const f16x8*)(ps + (size_t)k * 32);
        f16x8 bb = *(const f16x8*)(pb + (size_t)k * 32);
        accO = __builtin_amdgcn_mfma_f32_16x16x32_f16(a, bb, accO, 0, 0, 0);
        accS = __builtin_amdgcn_mfma_f32_16x16x32_f16(s, bb, accS, 0, 0, 0);
    }
    int t = w * 16 + ra;
    int q = qt * 16 + (lane >> 4) * 4;
    size_t base = (((size_t)ks * BB + b) * QP + q) * TP + t;
    #pragma unroll
    for (int r = 0; r < 4; ++r) {
        part_om[base + (size_t)r * TP] = accO[r];
        part_s[base + (size_t)r * TP] = accS[r];
    }
}

__global__ __launch_bounds__(256) void epilogue_kernel(
    const float* __restrict__ part_om, const float* __restrict__ part_s,
    const float* __restrict__ tmsum, const float* __restrict__ nsum,
    const float* __restrict__ ssum, const float* __restrict__ pred_logits,
    const float* __restrict__ pred_obj, const int* __restrict__ labels,
    float* __restrict__ out)
{
    int i = blockIdx.x * 256 + threadIdx.x;
    if (i >= BB * QQ * TT) return;
    int t = i % TT;
    int bq = i / TT;
    int b = bq / QQ, q = bq % QQ;
    float dO = 0.f, dS = 0.f;
    #pragma unroll
    for (int ks = 0; ks < KS; ++ks) {
        size_t o = (((size_t)ks * BB + b) * QP + q) * TP + t;
        dO += part_om[o];
        dS += part_s[o];
    }
    float ns = nsum[bq], ss = ssum[bq];
    float ts = tmsum[b * TT + t];
    float cmask = (ns - dO) * (1.f / PP);
    float cdice = 1.f - (2.f * dS + 1.f) / (ss + ts + 1.f);
    int label = labels[b * TT + t];
    float a0 = pred_obj[bq * 2], a1 = pred_obj[bq * 2 + 1];
    float prob;
    if (label == CC - 1) {
        prob = 1.f / (1.f + __expf(a0 - a1));
    } else {
        float pc = 1.f / (1.f + __expf(-pred_logits[(size_t)bq * CC + label]));
        float po = 1.f / (1.f + __expf(a1 - a0));
        prob = sqrtf(pc * po);
    }
    out[i] = 5.f * cmask - 2.f * prob + 5.f * cdice;
}

extern "C" void kernel_launch(void* const* d_in, const int* in_sizes, int n_in,
                              void* d_out, int out_size, void* d_ws, size_t ws_size,
                              hipStream_t stream) {
    const float* pred_logits = (const float*)d_in[0];
    const float* pred_obj    = (const float*)d_in[1];
    const float* pred_masks  = (const float*)d_in[2];
    const float* tgt_masks   = (const float*)d_in[3];
    const int*   tgt_labels  = (const int*)d_in[4];
    const float* coords      = (const float*)d_in[5];
    float* out = (float*)d_out;

    char* ws = (char*)d_ws;
    const size_t SZ_OM = (size_t)BB * QP * PP * 2;   // 22,478,848
    const size_t SZ_TM = (size_t)BB * TP * PP * 2;   // 12,845,056
    const size_t SZ_PT = (size_t)KS * BB * QP * TP * 4;  // 1,835,008
    _Float16* om  = (_Float16*)ws;
    _Float16* sg  = (_Float16*)(ws + SZ_OM);
    _Float16* tmm = (_Float16*)(ws + 2 * SZ_OM);
    float* part_om = (float*)(ws + 2 * SZ_OM + SZ_TM);
    float* part_s  = (float*)(ws + 2 * SZ_OM + SZ_TM + SZ_PT);
    float* tmsum   = (float*)(ws + 2 * SZ_OM + SZ_TM + 2 * SZ_PT);
    float* nsum    = tmsum + BB * TT;
    float* ssum    = nsum + BB * QQ;

    hipLaunchKernelGGL(sample_kernel, dim3(BB * TT + BB * QQ), dim3(1024), 0, stream,
                       tgt_masks, pred_masks, coords, tmm, om, sg, tmsum, nsum, ssum);
    hipLaunchKernelGGL(dot_mfma_kernel, dim3(QP / 16, BB, KS), dim3(256), 0, stream,
                       om, sg, tmm, part_om, part_s);
    hipLaunchKernelGGL(epilogue_kernel, dim3((BB * QQ * TT + 255) / 256), dim3(256),
                       0, stream,
                       part_om, part_s, tmsum, nsum, ssum,
                       pred_logits, pred_obj, tgt_labels, out);
}